// Round 11
// baseline (140.751 us; speedup 1.0000x reference)
//
#include <hip/hip_runtime.h>
#include <math.h>

// B=16,H=14,W=14,D=512, L=32, HID=512, A=512. fp32 in/out; bf16 in MFMA GEMM phases.
// Single-node mega-kernel: 256 blocks = (batch b, slot s) x 256 threads.
// All dataflow is per-batch, so sync is a 16-block per-batch barrier:
// RELAXED polls + one acquire fence (R10 result: acquire-per-poll costs ~55 us).
// 0xAA ws poison reads as negative int; epochs monotone positive -> no memset node.
#define NBLK 256

typedef __attribute__((ext_vector_type(8))) short short8;
typedef __attribute__((ext_vector_type(4))) float f32x4;

__device__ __forceinline__ unsigned f2bf_u(float x) {
    union { float f; unsigned u; } c; c.f = x;
    return (c.u + 0x7FFFu + ((c.u >> 16) & 1u)) >> 16;   // RNE, finite inputs
}
__device__ __forceinline__ unsigned short f2bf(float x) { return (unsigned short)f2bf_u(x); }
__device__ __forceinline__ unsigned pack2(float lo, float hi) {
    return f2bf_u(lo) | (f2bf_u(hi) << 16);
}
__device__ __forceinline__ uint4 pack8(const float4 a, const float4 b) {
    uint4 r;
    r.x = pack2(a.x, a.y); r.y = pack2(a.z, a.w);
    r.z = pack2(b.x, b.y); r.w = pack2(b.z, b.w);
    return r;
}

// flags[(b*16+s)*32] (128B apart). Each block of batch b stores its flag, then all
// 256 threads poll the batch's 16 flags (tid&15) RELAXED; one acquire fence each.
__device__ __forceinline__ void batchbar(int* flags, int epoch, int bb) {
    __syncthreads();
    if (threadIdx.x == 0)
        __hip_atomic_store(&flags[(bb * 16 + (blockIdx.x & 15)) * 32], epoch,
                           __ATOMIC_RELEASE, __HIP_MEMORY_SCOPE_AGENT);
    while (__hip_atomic_load(&flags[(bb * 16 + (threadIdx.x & 15)) * 32],
                             __ATOMIC_RELAXED, __HIP_MEMORY_SCOPE_AGENT) < epoch)
        __builtin_amdgcn_s_sleep(1);
    __builtin_amdgcn_fence(__ATOMIC_ACQUIRE, "agent");
    __syncthreads();
}

// ---- GEMM phase: C = A(512,512)·B(512,512)^T + bias[n] [* hmul] ; bf16 MFMA ----
// Tile (m0 = b*32 = batch rows, n0 = s*32); 4 waves split K (128 each) + LDS reduce.
template<int MODE>
__device__ __forceinline__ void gemm_phase(
    const float* __restrict__ Af, const unsigned short* __restrict__ Ab,
    const float* __restrict__ Bf, const float* __restrict__ bias,
    const float* __restrict__ hmul, float* __restrict__ C, char* smem, int bid)
{
    uint4* As = (uint4*)smem;               // 2048 slots (32KB)
    uint4* Bs = (uint4*)(smem + 32768);     // 2048 slots (32KB)
    float* red = (float*)smem;              // overlays As after sync (16KB)
    const int tid = threadIdx.x;

    const int m0 = (bid >> 4) * 32, n0 = (bid & 15) * 32;
    __syncthreads();
    #pragma unroll
    for (int j = 0; j < 8; ++j) {
        const int S = tid + 256 * j;
        const int i = S >> 6, ln = S & 63;
        const int t = i & 1, s = i >> 1;
        const int row  = t * 16 + (ln & 15);
        const int col8 = s * 4 + (ln >> 4);
        uint4 av;
        if (MODE == 0) {
            const float* ap = Af + (size_t)(m0 + row) * 512 + col8 * 8;
            av = pack8(*(const float4*)ap, *(const float4*)(ap + 4));
        } else {
            av = *(const uint4*)(Ab + (size_t)(m0 + row) * 512 + col8 * 8);
        }
        const float* bp = Bf + (size_t)(n0 + row) * 512 + col8 * 8;
        As[S] = av;
        Bs[S] = pack8(*(const float4*)bp, *(const float4*)(bp + 4));
    }
    __syncthreads();

    const int w = tid >> 6, ln = tid & 63;
    f32x4 acc[4];                            // fo = tm*2+tn
    #pragma unroll
    for (int fo = 0; fo < 4; ++fo) acc[fo] = (f32x4){0.f,0.f,0.f,0.f};
    #pragma unroll
    for (int sl = 0; sl < 4; ++sl) {
        const int s = 4 * w + sl;
        const short8 a0 = *(const short8*)&As[(2*s+0)*64 + ln];
        const short8 a1 = *(const short8*)&As[(2*s+1)*64 + ln];
        const short8 b0 = *(const short8*)&Bs[(2*s+0)*64 + ln];
        const short8 b1 = *(const short8*)&Bs[(2*s+1)*64 + ln];
        acc[0] = __builtin_amdgcn_mfma_f32_16x16x32_bf16(a0, b0, acc[0], 0, 0, 0);
        acc[1] = __builtin_amdgcn_mfma_f32_16x16x32_bf16(a0, b1, acc[1], 0, 0, 0);
        acc[2] = __builtin_amdgcn_mfma_f32_16x16x32_bf16(a1, b0, acc[2], 0, 0, 0);
        acc[3] = __builtin_amdgcn_mfma_f32_16x16x32_bf16(a1, b1, acc[3], 0, 0, 0);
    }
    __syncthreads();                         // done reading As/Bs
    #pragma unroll
    for (int fo = 0; fo < 4; ++fo)
        #pragma unroll
        for (int r = 0; r < 4; ++r)
            red[w*1024 + fo*256 + r*64 + ln] = acc[fo][r];
    __syncthreads();
    #pragma unroll
    for (int j = 0; j < 4; ++j) {
        const int o = tid + 256 * j;
        float v = red[o] + red[1024 + o] + red[2048 + o] + red[3072 + o];
        const int fo = o >> 8, r = (o >> 6) & 3, l2 = o & 63;
        // C/D layout: col = lane&15, row = (lane>>4)*4 + reg [m89-verified]
        const int m = m0 + (fo >> 1) * 16 + ((l2 >> 4) << 2) + r;
        const int n = n0 + (fo & 1) * 16 + (l2 & 15);
        v += bias[n];
        if (MODE == 1) v *= hmul[(size_t)m * 512 + n];
        C[(size_t)m * 512 + n] = v;
    }
}

// ---- scores phase: batch b, ptile slot (0..13), p0 = slot*14 ----
// f,w in registers; hlin staged flat in LDS; column rotation (j+2kc)&7 kills conflicts.
__device__ __forceinline__ void scores_phase(
    const float* __restrict__ maps, const float* __restrict__ hlin,
    const float* __restrict__ W_rect, const float* __restrict__ b_rect,
    float* __restrict__ scores_out, char* smem, int b, int p0)
{
    float* hls  = (float*)smem;              // 32*512 fp32 = 64KB
    float* redb = (float*)smem;              // overlays hls after main loop
    const int tid = threadIdx.x;
    const int kc = tid >> 4, pslot = tid & 15;
    const int p = p0 + (pslot < 14 ? pslot : 13);

    __syncthreads();
    const float4* hg = (const float4*)(hlin + (size_t)b * 32 * 512);
    float4* h4 = (float4*)hls;
    #pragma unroll
    for (int j = 0; j < 16; ++j) h4[tid + 256 * j] = hg[tid + 256 * j];

    int cofs[8];
    float4 fr[8], wr[8];
    const float* fb = maps + ((size_t)b * 196 + p) * 512 + kc * 32;
    const float* wb = W_rect + kc * 32;
    #pragma unroll
    for (int j = 0; j < 8; ++j) {
        cofs[j] = 4 * ((j + 2 * kc) & 7);
        fr[j] = *(const float4*)(fb + cofs[j]);
        wr[j] = *(const float4*)(wb + cofs[j]);
    }
    __syncthreads();

    float acc[32];
    for (int l = 0; l < 32; ++l) {
        const float* hrow = hls + l * 512 + kc * 32;
        float s0 = 0.f, s1 = 0.f, s2 = 0.f, s3 = 0.f;
        #pragma unroll
        for (int j = 0; j < 8; ++j) {
            const float4 h = *(const float4*)(hrow + cofs[j]);
            const float4 f = fr[j], w = wr[j];
            s0 += fmaxf(f.x + h.x, 0.f) * w.x;
            s1 += fmaxf(f.y + h.y, 0.f) * w.y;
            s2 += fmaxf(f.z + h.z, 0.f) * w.z;
            s3 += fmaxf(f.w + h.w, 0.f) * w.w;
        }
        acc[l] = (s0 + s1) + (s2 + s3);
    }
    __syncthreads();                         // done reading hls
    // bank-rotated partial layout: addr = pslot*545 + l*17 + kc
    #pragma unroll 4
    for (int l = 0; l < 32; ++l)
        redb[pslot * 545 + l * 17 + kc] = acc[l];
    __syncthreads();
    const float br = b_rect[0];
    for (int q = tid; q < 448; q += 256) {
        const int pp = q >> 5, l = q & 31;
        const float* rb = redb + pp * 545 + l * 17;
        float s = 0.f;
        #pragma unroll
        for (int k = 0; k < 16; ++k) s += rb[k];
        scores_out[((size_t)b * 32 + l) * 196 + p0 + pp] = s + br;
    }
}

// ---- softmax + ctx phase: (b = bid>>4, d-tile = bid&15) ----
__device__ __forceinline__ void softmax_ctx_phase(
    const float* __restrict__ maps, const float* __restrict__ scores,
    float* __restrict__ attn_out, unsigned short* __restrict__ ctx_out,
    char* smem, int bid)
{
    float* ft = (float*)smem;                // [196][36] = 28224 B
    float* at = (float*)(smem + 28224);      // [32][204] = 26112 B
    const int tid = threadIdx.x;

    const int b = bid >> 4, d0 = (bid & 15) * 32;
    __syncthreads();
    const float* fbase = maps + (size_t)b * 196 * 512 + d0;
    for (int fidx = tid; fidx < 1568; fidx += 256) {   // 196*32/4
        const int pp = fidx >> 3, q = fidx & 7;
        *(float4*)&ft[pp * 36 + q * 4] = *(const float4*)(fbase + (size_t)pp * 512 + q * 4);
    }
    const float4* sbase4 = (const float4*)(scores + (size_t)b * 32 * 196);
    for (int fidx = tid; fidx < 1568; fidx += 256) {   // 32 rows x 49 float4
        const int r = fidx / 49, c4 = fidx - r * 49;
        *(float4*)&at[r * 204 + c4 * 4] = sbase4[fidx];
    }
    __syncthreads();

    const int wave = tid >> 6, lane = tid & 63;
    #pragma unroll
    for (int rr = 0; rr < 8; ++rr) {
        const int row = wave * 8 + rr;
        float v[4];
        #pragma unroll
        for (int i = 0; i < 4; ++i) {
            const int pp = lane + 64 * i;
            v[i] = (pp < 196) ? at[row * 204 + pp] : -INFINITY;
        }
        float m = fmaxf(fmaxf(v[0], v[1]), fmaxf(v[2], v[3]));
        for (int off = 32; off > 0; off >>= 1) m = fmaxf(m, __shfl_down(m, off));
        m = __shfl(m, 0);
        float e[4], s = 0.f;
        #pragma unroll
        for (int i = 0; i < 4; ++i) {
            const int pp = lane + 64 * i;
            e[i] = (pp < 196) ? __expf(v[i] - m) : 0.f;
            s += e[i];
        }
        for (int off = 32; off > 0; off >>= 1) s += __shfl_down(s, off);
        s = __shfl(s, 0);
        const float inv = 1.f / s;
        #pragma unroll
        for (int i = 0; i < 4; ++i) {
            const int pp = lane + 64 * i;
            if (pp < 196) at[row * 204 + pp] = e[i] * inv;
        }
    }
    __syncthreads();

    if ((bid & 15) == 0) {
        float4* ao4 = (float4*)(attn_out + (size_t)b * 32 * 196);
        for (int fidx = tid; fidx < 1568; fidx += 256) {
            const int r = fidx / 49, c4 = fidx - r * 49;
            ao4[fidx] = *(const float4*)&at[r * 204 + c4 * 4];
        }
    }

    const int l = tid >> 3, d4 = tid & 7;
    float ax = 0.f, ay = 0.f, az = 0.f, aw = 0.f;
    for (int p4 = 0; p4 < 49; ++p4) {
        const float4 a4 = *(const float4*)&at[l * 204 + p4 * 4];
        const float4 f0 = *(const float4*)&ft[(p4 * 4 + 0) * 36 + d4 * 4];
        const float4 f1 = *(const float4*)&ft[(p4 * 4 + 1) * 36 + d4 * 4];
        const float4 f2 = *(const float4*)&ft[(p4 * 4 + 2) * 36 + d4 * 4];
        const float4 f3 = *(const float4*)&ft[(p4 * 4 + 3) * 36 + d4 * 4];
        ax += a4.x * f0.x + a4.y * f1.x + a4.z * f2.x + a4.w * f3.x;
        ay += a4.x * f0.y + a4.y * f1.y + a4.z * f2.y + a4.w * f3.y;
        az += a4.x * f0.z + a4.y * f1.z + a4.z * f2.z + a4.w * f3.z;
        aw += a4.x * f0.w + a4.y * f1.w + a4.z * f2.w + a4.w * f3.w;
    }
    ushort4 o;
    o.x = f2bf(ax); o.y = f2bf(ay); o.z = f2bf(az); o.w = f2bf(aw);
    *(ushort4*)(ctx_out + ((size_t)b * 32 + l) * 512 + d0 + d4 * 4) = o;
    __syncthreads();
}

__global__ __launch_bounds__(256) void coatt_mega_kernel(
    const float* __restrict__ maps, const float* __restrict__ hiddens,
    const float* __restrict__ W_hidden, const float* __restrict__ b_hidden,
    const float* __restrict__ W_rect, const float* __restrict__ b_rect,
    const float* __restrict__ W_co, const float* __restrict__ b_co,
    float* __restrict__ out_co, float* __restrict__ out_attn,
    float* __restrict__ scores, unsigned short* __restrict__ ctx16,
    int* __restrict__ flags)
{
    __shared__ __align__(16) char smem[65536];
    const int bid = blockIdx.x;
    const int b = bid >> 4, slot = bid & 15;

    // Phase A: hlin tile (rows b*32..+31, cols slot*32..+31) -> out_co (temp)
    gemm_phase<0>(hiddens, (const unsigned short*)nullptr, W_hidden, b_hidden,
                  (const float*)nullptr, out_co, smem, bid);
    batchbar(flags, 1, b);
    // Phase B: raw scores for (b, ptile slot) -> ws (slots 14,15 idle)
    if (slot < 14)
        scores_phase(maps, out_co, W_rect, b_rect, scores, smem, b, slot * 14);
    batchbar(flags, 2, b);
    // Phase C: softmax (-> out_attn) + ctx d-tile (bf16 -> ws)
    softmax_ctx_phase(maps, scores, out_attn, ctx16, smem, bid);
    batchbar(flags, 3, b);
    // Phase D: out tile = (ctx @ W_co^T + b_co) * hiddens
    gemm_phase<1>((const float*)nullptr, ctx16, W_co, b_co, hiddens, out_co, smem, bid);
}

extern "C" void kernel_launch(void* const* d_in, const int* in_sizes, int n_in,
                              void* d_out, int out_size, void* d_ws, size_t ws_size,
                              hipStream_t stream)
{
    const float* maps     = (const float*)d_in[0];
    const float* hiddens  = (const float*)d_in[1];
    const float* W_hidden = (const float*)d_in[2];
    const float* b_hidden = (const float*)d_in[3];
    const float* W_rect   = (const float*)d_in[4];
    const float* b_rect   = (const float*)d_in[5];
    const float* W_co     = (const float*)d_in[6];
    const float* b_co     = (const float*)d_in[7];

    float* out_co   = (float*)d_out;                    // (512,512): hlin, then final
    float* out_attn = out_co + (size_t)512 * 512;       // (512,196)

    char* ws = (char*)d_ws;
    float*          scores = (float*)(ws);                          // 401 KB
    unsigned short* ctx16  = (unsigned short*)(ws + (1 << 20));     // 512 KB
    int*            flags  = (int*)(ws + (4 << 20));                // 256*128B

    hipLaunchKernelGGL(coatt_mega_kernel, dim3(NBLK), dim3(256), 0, stream,
                       maps, hiddens, W_hidden, b_hidden, W_rect, b_rect,
                       W_co, b_co, out_co, out_attn, scores, ctx16, flags);
}

// Round 12
// 106.047 us; speedup vs baseline: 1.3272x; 1.3272x over previous
//
#include <hip/hip_runtime.h>
#include <math.h>

// B=16,H=14,W=14,D=512, L=32, HID=512, A=512. fp32 in/out; bf16 inside MFMA GEMMs.
// R12: 3 kernels, no global sync. gemm1 -> mid (scores+softmax+ctx fused per
// (b, l-pair)) -> gemm2(+epilogue). Graph-node count is the lever (~7-9 us/node).

typedef __attribute__((ext_vector_type(8))) short short8;
typedef __attribute__((ext_vector_type(4))) float f32x4;

__device__ __forceinline__ unsigned f2bf_u(float x) {
    union { float f; unsigned u; } c; c.f = x;
    return (c.u + 0x7FFFu + ((c.u >> 16) & 1u)) >> 16;   // RNE, finite inputs
}
__device__ __forceinline__ unsigned pack2(float lo, float hi) {
    return f2bf_u(lo) | (f2bf_u(hi) << 16);
}
__device__ __forceinline__ uint4 pack8(const float4 a, const float4 b) {
    uint4 r;
    r.x = pack2(a.x, a.y); r.y = pack2(a.z, a.w);
    r.z = pack2(b.x, b.y); r.w = pack2(b.z, b.w);
    return r;
}

// ---- GEMM: C = A(512,512)_f32 · B(512,512)_f32^T + bias[n] [* hmul] ; bf16 MFMA ----
// grid 256: tile (m0=(bid>>4)*32, n0=(bid&15)*32); 4 waves split K + LDS reduce.
template<int HMUL>
__global__ __launch_bounds__(256) void gemm_kernel(
    const float* __restrict__ Af, const float* __restrict__ Bf,
    const float* __restrict__ bias, const float* __restrict__ hmul,
    float* __restrict__ C)
{
    __shared__ __align__(16) char smem[65536];
    uint4* As = (uint4*)smem;               // 2048 slots (32KB)
    uint4* Bs = (uint4*)(smem + 32768);     // 2048 slots (32KB)
    float* red = (float*)smem;              // overlays As after sync (16KB)
    const int tid = threadIdx.x, bid = blockIdx.x;

    const int m0 = (bid >> 4) * 32, n0 = (bid & 15) * 32;
    #pragma unroll
    for (int j = 0; j < 8; ++j) {
        const int S = tid + 256 * j;
        const int i = S >> 6, ln = S & 63;
        const int t = i & 1, s = i >> 1;
        const int row  = t * 16 + (ln & 15);
        const int col8 = s * 4 + (ln >> 4);
        const float* ap = Af + (size_t)(m0 + row) * 512 + col8 * 8;
        const float* bp = Bf + (size_t)(n0 + row) * 512 + col8 * 8;
        As[S] = pack8(*(const float4*)ap, *(const float4*)(ap + 4));
        Bs[S] = pack8(*(const float4*)bp, *(const float4*)(bp + 4));
    }
    __syncthreads();

    const int w = tid >> 6, ln = tid & 63;
    f32x4 acc[4];                            // fo = tm*2+tn
    #pragma unroll
    for (int fo = 0; fo < 4; ++fo) acc[fo] = (f32x4){0.f,0.f,0.f,0.f};
    #pragma unroll
    for (int sl = 0; sl < 4; ++sl) {
        const int s = 4 * w + sl;
        const short8 a0 = *(const short8*)&As[(2*s+0)*64 + ln];
        const short8 a1 = *(const short8*)&As[(2*s+1)*64 + ln];
        const short8 b0 = *(const short8*)&Bs[(2*s+0)*64 + ln];
        const short8 b1 = *(const short8*)&Bs[(2*s+1)*64 + ln];
        acc[0] = __builtin_amdgcn_mfma_f32_16x16x32_bf16(a0, b0, acc[0], 0, 0, 0);
        acc[1] = __builtin_amdgcn_mfma_f32_16x16x32_bf16(a0, b1, acc[1], 0, 0, 0);
        acc[2] = __builtin_amdgcn_mfma_f32_16x16x32_bf16(a1, b0, acc[2], 0, 0, 0);
        acc[3] = __builtin_amdgcn_mfma_f32_16x16x32_bf16(a1, b1, acc[3], 0, 0, 0);
    }
    __syncthreads();                         // done reading As/Bs
    #pragma unroll
    for (int fo = 0; fo < 4; ++fo)
        #pragma unroll
        for (int r = 0; r < 4; ++r)
            red[w*1024 + fo*256 + r*64 + ln] = acc[fo][r];
    __syncthreads();
    #pragma unroll
    for (int j = 0; j < 4; ++j) {
        const int o = tid + 256 * j;
        float v = red[o] + red[1024 + o] + red[2048 + o] + red[3072 + o];
        const int fo = o >> 8, r = (o >> 6) & 3, l2 = o & 63;
        // C/D layout: col = lane&15, row = (lane>>4)*4 + reg [m89-verified]
        const int m = m0 + (fo >> 1) * 16 + ((l2 >> 4) << 2) + r;
        const int n = n0 + (fo & 1) * 16 + (l2 & 15);
        v += bias[n];
        if (HMUL) v *= hmul[(size_t)m * 512 + n];
        C[(size_t)m * 512 + n] = v;
    }
}

// ---- mid kernel: block (b = bx>>4, s = bx&15) owns l0 = 2s, l0+1 ----
// scores (196x2) -> softmax -> attn(out, fp32) -> ctx rows (fp32 -> ws)
__global__ __launch_bounds__(256) void mid_kernel(
    const float* __restrict__ maps, const float* __restrict__ hlin,
    const float* __restrict__ W_rect, const float* __restrict__ b_rect,
    float* __restrict__ attn_out, float* __restrict__ ctx_out)
{
    const int b = blockIdx.x >> 4, s = blockIdx.x & 15;
    const int l0 = 2 * s;
    const int tid = threadIdx.x;
    const int pi = tid >> 4, k = tid & 15;

    __shared__ float h0[512], h1[512], wv[512];     // 6 KB
    __shared__ float ftile[16 * 516];               // 33 KB
    __shared__ float red0[208 * 16], red1[208 * 16];// 26.6 KB
    __shared__ float sm[2 * 208];                   // 1.7 KB

    // stage hlin rows l0,l0+1 and W_rect
    {
        const float4* H0 = (const float4*)(hlin + ((size_t)b * 32 + l0) * 512);
        const float4* H1 = (const float4*)(hlin + ((size_t)b * 32 + l0 + 1) * 512);
        const float4* WV = (const float4*)W_rect;
        if (tid < 128) { ((float4*)h0)[tid] = H0[tid]; ((float4*)wv)[tid] = WV[tid]; }
        else           { ((float4*)h1)[tid - 128] = H1[tid - 128]; }
    }
    __syncthreads();

    // hoist this thread's a-set (32 elems, bank-rotated) into registers
    int aoff[8];
    float4 h0r[8], h1r[8], wr[8];
    #pragma unroll
    for (int j = 0; j < 8; ++j) {
        aoff[j] = k * 32 + ((j + k) & 7) * 4;
        h0r[j] = *(const float4*)&h0[aoff[j]];
        h1r[j] = *(const float4*)&h1[aoff[j]];
        wr[j]  = *(const float4*)&wv[aoff[j]];
    }

    const float* mb = maps + (size_t)b * 196 * 512;

    // scores: 13 chunks of 16 p-rows through LDS
    for (int c = 0; c < 13; ++c) {
        __syncthreads();
        #pragma unroll
        for (int it = 0; it < 8; ++it) {
            const int idx = tid + 256 * it;      // 0..2047 float4
            const int r = idx >> 7, c4 = idx & 127;
            int p = c * 16 + r; if (p > 195) p = 195;
            *(float4*)&ftile[r * 516 + c4 * 4] = *(const float4*)(mb + (size_t)p * 512 + c4 * 4);
        }
        __syncthreads();
        float s0 = 0.f, s1 = 0.f;
        #pragma unroll
        for (int j = 0; j < 8; ++j) {
            const float4 f = *(const float4*)&ftile[pi * 516 + aoff[j]];
            const float4 A = h0r[j], Bv = h1r[j], W = wr[j];
            s0 += fmaxf(f.x + A.x, 0.f) * W.x + fmaxf(f.y + A.y, 0.f) * W.y
                + fmaxf(f.z + A.z, 0.f) * W.z + fmaxf(f.w + A.w, 0.f) * W.w;
            s1 += fmaxf(f.x + Bv.x, 0.f) * W.x + fmaxf(f.y + Bv.y, 0.f) * W.y
                + fmaxf(f.z + Bv.z, 0.f) * W.z + fmaxf(f.w + Bv.w, 0.f) * W.w;
        }
        const int p = c * 16 + pi;
        red0[p * 16 + k] = s0;
        red1[p * 16 + k] = s1;
    }
    __syncthreads();

    // finalize raw scores into sm[l][p]
    const float br = b_rect[0];
    for (int idx = tid; idx < 392; idx += 256) {
        const int l = idx & 1, p = idx >> 1;
        const float* rb = (l ? red1 : red0) + p * 16;
        const float4 a = *(const float4*)rb,      bq = *(const float4*)(rb + 4);
        const float4 cq = *(const float4*)(rb + 8), dq = *(const float4*)(rb + 12);
        sm[l * 208 + p] = (a.x + a.y + a.z + a.w) + (bq.x + bq.y + bq.z + bq.w)
                        + (cq.x + cq.y + cq.z + cq.w) + (dq.x + dq.y + dq.z + dq.w) + br;
    }
    __syncthreads();

    // softmax: wave 0 -> l0, wave 1 -> l0+1
    const int wave = tid >> 6, lane = tid & 63;
    if (wave < 2) {
        float v[4];
        #pragma unroll
        for (int i = 0; i < 4; ++i) {
            const int p = lane + 64 * i;
            v[i] = (p < 196) ? sm[wave * 208 + p] : -INFINITY;
        }
        float m = fmaxf(fmaxf(v[0], v[1]), fmaxf(v[2], v[3]));
        for (int off = 32; off > 0; off >>= 1) m = fmaxf(m, __shfl_down(m, off));
        m = __shfl(m, 0);
        float e[4], ssum = 0.f;
        #pragma unroll
        for (int i = 0; i < 4; ++i) {
            const int p = lane + 64 * i;
            e[i] = (p < 196) ? __expf(v[i] - m) : 0.f;
            ssum += e[i];
        }
        for (int off = 32; off > 0; off >>= 1) ssum += __shfl_down(ssum, off);
        ssum = __shfl(ssum, 0);
        const float inv = 1.f / ssum;
        float* ao = attn_out + ((size_t)b * 32 + l0 + wave) * 196;
        #pragma unroll
        for (int i = 0; i < 4; ++i) {
            const int p = lane + 64 * i;
            if (p < 196) {
                const float at = e[i] * inv;
                sm[wave * 208 + p] = at;
                ao[p] = at;
            }
        }
    }
    __syncthreads();

    // ctx pass: thread owns d0 = 2*tid; coalesced f2 stream over maps
    const int d0 = tid * 2;
    float a0 = 0.f, a1 = 0.f, c0 = 0.f, c1 = 0.f;
    for (int p = 0; p < 196; ++p) {
        const float2 f = *(const float2*)(mb + (size_t)p * 512 + d0);
        const float w0 = sm[p], w1 = sm[208 + p];
        a0 += w0 * f.x; a1 += w0 * f.y;
        c0 += w1 * f.x; c1 += w1 * f.y;
    }
    float2 o0; o0.x = a0; o0.y = a1;
    float2 o1; o1.x = c0; o1.y = c1;
    *(float2*)(ctx_out + ((size_t)b * 32 + l0) * 512 + d0)     = o0;
    *(float2*)(ctx_out + ((size_t)b * 32 + l0 + 1) * 512 + d0) = o1;
}

extern "C" void kernel_launch(void* const* d_in, const int* in_sizes, int n_in,
                              void* d_out, int out_size, void* d_ws, size_t ws_size,
                              hipStream_t stream)
{
    const float* maps     = (const float*)d_in[0];
    const float* hiddens  = (const float*)d_in[1];
    const float* W_hidden = (const float*)d_in[2];
    const float* b_hidden = (const float*)d_in[3];
    const float* W_rect   = (const float*)d_in[4];
    const float* b_rect   = (const float*)d_in[5];
    const float* W_co     = (const float*)d_in[6];
    const float* b_co     = (const float*)d_in[7];

    float* out_co   = (float*)d_out;                    // (512,512): hlin temp, then final
    float* out_attn = out_co + (size_t)512 * 512;       // (512,196)
    float* ctx      = (float*)d_ws;                     // (512,512) fp32 = 1 MB

    // 1) hlin = hiddens @ W_hidden^T + b_hidden -> out_co
    hipLaunchKernelGGL((gemm_kernel<0>), dim3(256), dim3(256), 0, stream,
                       hiddens, W_hidden, b_hidden, (const float*)nullptr, out_co);
    // 2) scores + softmax (-> out_attn) + ctx (fp32 -> ws)
    hipLaunchKernelGGL(mid_kernel, dim3(256), dim3(256), 0, stream,
                       maps, out_co, W_rect, b_rect, out_attn, ctx);
    // 3) out_co = (ctx @ W_co^T + b_co) * hiddens
    hipLaunchKernelGGL((gemm_kernel<1>), dim3(256), dim3(256), 0, stream,
                       ctx, W_co, b_co, hiddens, out_co);
}